// Round 2
// baseline (90.422 us; speedup 1.0000x reference)
//
#include <hip/hip_runtime.h>
#include <hip/hip_cooperative_groups.h>

namespace cg = cooperative_groups;

// AUCM loss via moment expansion, fused into ONE cooperative kernel dispatch.
//
// softplus(-d) on d in (-1,1):  ln2 - d/2 + d^2/8 - d^4/192 + d^6/2880 - 17 d^8/645120
// (Taylor of log(2cosh(d/2)) - d/2; max error < 3e-6 on [-1,1]).
// Sum over (pos i, neg j) pairs of poly(p_i - p_j) = binomial combination of
// power sums A_t = sum_{pos} p^t, B_t = sum_{neg} p^t, t = 0..8.
//
// Single dispatch: per-class blocks write ws[c] (mean) and ws[C+c] (valid),
// grid-wide sync (hipLaunchCooperativeKernel — blessed by the harness), then
// block 0 reduces the 2*C floats to the scalar. Poison-tolerant with NO init:
// every ws slot read after the barrier is written this iteration. Cross-XCD
// visibility via agent-scope atomic store/load (per-XCD L2s not coherent for
// plain accesses).

#define NMOM 9

__global__ __launch_bounds__(256) void aucm_fused_kernel(
    const float* __restrict__ logits,
    const float* __restrict__ targets,
    float* __restrict__ ws,    // ws[0..C-1] = per-class mean, ws[C..2C-1] = valid
    float* __restrict__ out,
    int B, int C)
{
    const int c   = blockIdx.x;     // one block per class
    const int tid = threadIdx.x;    // 256 threads

    float pm[NMOM];   // sum over positives of p^k  (targets are exactly 0.0/1.0)
    float sm[NMOM];   // sum over ALL samples of p^k; negatives = sm - pm
#pragma unroll
    for (int k = 0; k < NMOM; ++k) { pm[k] = 0.0f; sm[k] = 0.0f; }

    for (int b = tid; b < B; b += 256) {
        const float l = logits[b * C + c];
        const float t = targets[b * C + c];          // 0.0 or 1.0
        const float p = 1.0f / (1.0f + __expf(-l));  // sigmoid
        float pw = 1.0f;
#pragma unroll
        for (int k = 0; k < NMOM; ++k) {
            sm[k] += pw;                  // all-sample moment
            pm[k] = fmaf(t, pw, pm[k]);   // positive moment, branch-free
            pw *= p;
        }
    }

    // reduce across the 4 waves of the block
    const int lane = tid & 63;
    const int wave = tid >> 6;
    __shared__ float red[2 * NMOM][4];

#pragma unroll
    for (int k = 0; k < NMOM; ++k) {
        float v = pm[k];
#pragma unroll
        for (int off = 32; off > 0; off >>= 1) v += __shfl_down(v, off);
        if (lane == 0) red[k][wave] = v;
        float w = sm[k];
#pragma unroll
        for (int off = 32; off > 0; off >>= 1) w += __shfl_down(w, off);
        if (lane == 0) red[NMOM + k][wave] = w;
    }
    __syncthreads();

    if (tid == 0) {
        float A[NMOM], Bv[NMOM];
#pragma unroll
        for (int k = 0; k < NMOM; ++k) {
            A[k] = red[k][0] + red[k][1] + red[k][2] + red[k][3];
            const float s = red[NMOM + k][0] + red[NMOM + k][1]
                          + red[NMOM + k][2] + red[NMOM + k][3];
            Bv[k] = s - A[k];   // negative moments
        }
        // sum over pairs of (p_i - p_j)^k via binomial expansion
        const float s1 = A[1]*Bv[0] - A[0]*Bv[1];
        const float s2 = A[2]*Bv[0] - 2.0f*A[1]*Bv[1] + A[0]*Bv[2];
        const float s4 = A[4]*Bv[0] - 4.0f*A[3]*Bv[1] + 6.0f*A[2]*Bv[2]
                       - 4.0f*A[1]*Bv[3] + A[0]*Bv[4];
        const float s6 = A[6]*Bv[0] - 6.0f*A[5]*Bv[1] + 15.0f*A[4]*Bv[2]
                       - 20.0f*A[3]*Bv[3] + 15.0f*A[2]*Bv[4] - 6.0f*A[1]*Bv[5]
                       + A[0]*Bv[6];
        const float s8 = A[8]*Bv[0] - 8.0f*A[7]*Bv[1] + 28.0f*A[6]*Bv[2]
                       - 56.0f*A[5]*Bv[3] + 70.0f*A[4]*Bv[4] - 56.0f*A[3]*Bv[5]
                       + 28.0f*A[2]*Bv[6] - 8.0f*A[1]*Bv[7] + A[0]*Bv[8];

        const float cnt = A[0] * Bv[0];
        const float num = 0.69314718056f * cnt
                        - 0.5f            * s1
                        + 0.125f          * s2
                        - 5.20833333e-3f  * s4   // 1/192
                        + 3.47222222e-4f  * s6   // 1/2880
                        - 2.63516865e-5f  * s8;  // 17/645120

        const bool  valid = (cnt > 0.0f);
        const float mean  = valid ? num / fmaxf(cnt, 1.0f) : 0.0f;
        const float vf    = valid ? 1.0f : 0.0f;

        // agent(device)-scope stores: visible across XCDs after grid sync
        __hip_atomic_store(&ws[c],     mean, __ATOMIC_RELAXED, __HIP_MEMORY_SCOPE_AGENT);
        __hip_atomic_store(&ws[C + c], vf,   __ATOMIC_RELAXED, __HIP_MEMORY_SCOPE_AGENT);
    }

    cg::this_grid().sync();

    if (blockIdx.x == 0) {
        float m = 0.0f, v = 0.0f;
        if (tid < C) {
            m = __hip_atomic_load(&ws[tid],     __ATOMIC_RELAXED, __HIP_MEMORY_SCOPE_AGENT);
            v = __hip_atomic_load(&ws[C + tid], __ATOMIC_RELAXED, __HIP_MEMORY_SCOPE_AGENT);
        }
#pragma unroll
        for (int off = 32; off > 0; off >>= 1) {
            m += __shfl_down(m, off);
            v += __shfl_down(v, off);
        }
        __shared__ float sm2[4], sv2[4];
        if (lane == 0) { sm2[wave] = m; sv2[wave] = v; }
        __syncthreads();
        if (tid == 0) {
            const float ms = sm2[0] + sm2[1] + sm2[2] + sm2[3];
            const float vs = sv2[0] + sv2[1] + sv2[2] + sv2[3];
            out[0] = (vs > 0.0f) ? ms / fmaxf(vs, 1.0f) : 0.0f;
        }
    }
}

extern "C" void kernel_launch(void* const* d_in, const int* in_sizes, int n_in,
                              void* d_out, int out_size, void* d_ws, size_t ws_size,
                              hipStream_t stream) {
    const float* logits  = (const float*)d_in[0];
    const float* targets = (const float*)d_in[1];
    float* ws  = (float*)d_ws;
    float* out = (float*)d_out;

    int C = 128;
    int B = in_sizes[0] / C;   // 1024

    void* args[] = { (void*)&logits, (void*)&targets, (void*)&ws, (void*)&out,
                     (void*)&B, (void*)&C };
    hipLaunchCooperativeKernel((void*)aucm_fused_kernel, dim3(C), dim3(256),
                               args, 0, stream);
}

// Round 3
// 62.073 us; speedup vs baseline: 1.4567x; 1.4567x over previous
//
#include <hip/hip_runtime.h>

// AUCM loss via moment expansion — ONE ordinary kernel dispatch, no init.
//
// softplus(-d) on d in (-1,1):  ln2 - d/2 + d^2/8 - d^4/192 + d^6/2880 - 17 d^8/645120
// (Taylor of log(2cosh(d/2)) - d/2; max error < 3e-6 on [-1,1]).
// Sum over (pos i, neg j) pairs of poly(p_i - p_j) = binomial combination of
// power sums A_t = sum_{pos} p^t, B_t = sum_{neg} p^t, t = 0..8.
//
// Cross-block handoff WITHOUT workspace init (ws is poison-filled each iter):
// block c stores {mean, valid, checksum = u(mean)^u(valid)^MAGIC} via
// device(agent)-scope atomics (coherent across XCDs). Block 0 spins until each
// class's checksum matches its data. Uniform poison P passes only if P==MAGIC
// (one excluded 32-bit pattern); a stale/fresh mix passes only if the stale
// word is bit-identical to the intended value (harmless). Grid=128 <= 256 CUs,
// so producer blocks are never starved by the spinning block.

#define NMOM 9
#define MAGIC 0x7C3A9E15u

__global__ __launch_bounds__(256) void aucm_onepass_kernel(
    const float* __restrict__ logits,
    const float* __restrict__ targets,
    float* __restrict__ ws,   // [0..C) mean, [C..2C) valid, [2C..3C) checksum
    float* __restrict__ out,
    int B, int C)
{
    const int c    = blockIdx.x;     // one block per class
    const int tid  = threadIdx.x;    // 256 threads
    const int lane = tid & 63;
    const int wave = tid >> 6;

    float pm[NMOM];       // sum over positives of p^k (targets are exactly 0/1)
    float sq[NMOM];       // sum over ALL samples of p^k; sq[0] unused (== B)
#pragma unroll
    for (int k = 0; k < NMOM; ++k) { pm[k] = 0.0f; sq[k] = 0.0f; }

    if (B == 1024) {
        // fast path: fully unrolled, loads batched ahead of compute
        float l[4], t[4], p[4];
#pragma unroll
        for (int i = 0; i < 4; ++i) {
            const int b = tid + i * 256;
            l[i] = logits[b * C + c];
            t[i] = targets[b * C + c];
        }
#pragma unroll
        for (int i = 0; i < 4; ++i) p[i] = 1.0f / (1.0f + __expf(-l[i]));
#pragma unroll
        for (int i = 0; i < 4; ++i) {
            pm[0] += t[i];
            float pw = p[i];
#pragma unroll
            for (int k = 1; k < NMOM; ++k) {
                sq[k] += pw;
                pm[k] = fmaf(t[i], pw, pm[k]);
                pw *= p[i];
            }
        }
    } else {
        for (int b = tid; b < B; b += 256) {
            const float l = logits[b * C + c];
            const float t = targets[b * C + c];
            const float p = 1.0f / (1.0f + __expf(-l));
            pm[0] += t;
            float pw = p;
            for (int k = 1; k < NMOM; ++k) {
                sq[k] += pw;
                pm[k] = fmaf(t, pw, pm[k]);
                pw *= p;
            }
        }
    }

    // reduce 17 values (pm[0..8], sq[1..8]) across the 4 waves
    __shared__ float red[17][4];
#pragma unroll
    for (int k = 0; k < NMOM; ++k) {
        float v = pm[k];
#pragma unroll
        for (int off = 32; off > 0; off >>= 1) v += __shfl_down(v, off);
        if (lane == 0) red[k][wave] = v;
    }
#pragma unroll
    for (int k = 1; k < NMOM; ++k) {
        float w = sq[k];
#pragma unroll
        for (int off = 32; off > 0; off >>= 1) w += __shfl_down(w, off);
        if (lane == 0) red[8 + k][wave] = w;
    }
    __syncthreads();

    if (tid == 0) {
        float A[NMOM], Bv[NMOM];
#pragma unroll
        for (int k = 0; k < NMOM; ++k)
            A[k] = red[k][0] + red[k][1] + red[k][2] + red[k][3];
        Bv[0] = (float)B - A[0];
#pragma unroll
        for (int k = 1; k < NMOM; ++k) {
            const float s = red[8 + k][0] + red[8 + k][1]
                          + red[8 + k][2] + red[8 + k][3];
            Bv[k] = s - A[k];
        }
        // sum over pairs of (p_i - p_j)^k via binomial expansion
        const float s1 = A[1]*Bv[0] - A[0]*Bv[1];
        const float s2 = A[2]*Bv[0] - 2.0f*A[1]*Bv[1] + A[0]*Bv[2];
        const float s4 = A[4]*Bv[0] - 4.0f*A[3]*Bv[1] + 6.0f*A[2]*Bv[2]
                       - 4.0f*A[1]*Bv[3] + A[0]*Bv[4];
        const float s6 = A[6]*Bv[0] - 6.0f*A[5]*Bv[1] + 15.0f*A[4]*Bv[2]
                       - 20.0f*A[3]*Bv[3] + 15.0f*A[2]*Bv[4] - 6.0f*A[1]*Bv[5]
                       + A[0]*Bv[6];
        const float s8 = A[8]*Bv[0] - 8.0f*A[7]*Bv[1] + 28.0f*A[6]*Bv[2]
                       - 56.0f*A[5]*Bv[3] + 70.0f*A[4]*Bv[4] - 56.0f*A[3]*Bv[5]
                       + 28.0f*A[2]*Bv[6] - 8.0f*A[1]*Bv[7] + A[0]*Bv[8];

        const float cnt = A[0] * Bv[0];
        const float num = 0.69314718056f * cnt
                        - 0.5f            * s1
                        + 0.125f          * s2
                        - 5.20833333e-3f  * s4   // 1/192
                        + 3.47222222e-4f  * s6   // 1/2880
                        - 2.63516865e-5f  * s8;  // 17/645120

        const bool  valid = (cnt > 0.0f);
        const float mean  = valid ? num / fmaxf(cnt, 1.0f) : 0.0f;
        const float vf    = valid ? 1.0f : 0.0f;

        unsigned* w32 = reinterpret_cast<unsigned*>(ws);
        const unsigned um = __float_as_uint(mean);
        const unsigned uv = __float_as_uint(vf);
        __hip_atomic_store(&w32[c],         um, __ATOMIC_RELAXED, __HIP_MEMORY_SCOPE_AGENT);
        __hip_atomic_store(&w32[C + c],     uv, __ATOMIC_RELAXED, __HIP_MEMORY_SCOPE_AGENT);
        __hip_atomic_store(&w32[2 * C + c], um ^ uv ^ MAGIC,
                           __ATOMIC_RELEASE, __HIP_MEMORY_SCOPE_AGENT);
    }

    // block 0 finalizes once every class's triple validates
    if (c == 0) {
        float m = 0.0f, v = 0.0f;
        if (tid < C) {
            unsigned* w32 = reinterpret_cast<unsigned*>(ws);
            unsigned um, uv, uc;
            do {
                um = __hip_atomic_load(&w32[tid],         __ATOMIC_RELAXED, __HIP_MEMORY_SCOPE_AGENT);
                uv = __hip_atomic_load(&w32[C + tid],     __ATOMIC_RELAXED, __HIP_MEMORY_SCOPE_AGENT);
                uc = __hip_atomic_load(&w32[2 * C + tid], __ATOMIC_ACQUIRE, __HIP_MEMORY_SCOPE_AGENT);
            } while (uc != (um ^ uv ^ MAGIC));
            m = __uint_as_float(um);
            v = __uint_as_float(uv);
        }
#pragma unroll
        for (int off = 32; off > 0; off >>= 1) {
            m += __shfl_down(m, off);
            v += __shfl_down(v, off);
        }
        __shared__ float sm2[2], sv2[2];
        if (tid < C && lane == 0) { sm2[wave] = m; sv2[wave] = v; }
        __syncthreads();
        if (tid == 0) {
            const float ms = sm2[0] + sm2[1];
            const float vs = sv2[0] + sv2[1];
            out[0] = (vs > 0.0f) ? ms / fmaxf(vs, 1.0f) : 0.0f;
        }
    }
}

extern "C" void kernel_launch(void* const* d_in, const int* in_sizes, int n_in,
                              void* d_out, int out_size, void* d_ws, size_t ws_size,
                              hipStream_t stream) {
    const float* logits  = (const float*)d_in[0];
    const float* targets = (const float*)d_in[1];
    float* ws  = (float*)d_ws;
    float* out = (float*)d_out;

    const int C = 128;
    const int B = in_sizes[0] / C;   // 1024

    aucm_onepass_kernel<<<C, 256, 0, stream>>>(logits, targets, ws, out, B, C);
}